// Round 1
// baseline (324.532 us; speedup 1.0000x reference)
//
#include <hip/hip_runtime.h>
#include <cstddef>

#define EPSV 1e-5f

// x (16,128,56,56) -> xb (896,128,56): xb[n*56+w][c][h] = x[n][c][h][w]
__global__ __launch_bounds__(256) void k_transpose_in(const float* __restrict__ x,
                                                      float* __restrict__ xb) {
  int nc = blockIdx.x;               // n*128 + c
  int n = nc >> 7, c = nc & 127;
  __shared__ float t[56][57];
  const float* src = x + (size_t)nc * 3136;
  for (int idx = threadIdx.x; idx < 3136; idx += 256)
    t[idx / 56][idx % 56] = src[idx];        // coalesced read (w contiguous)
  __syncthreads();
  for (int idx = threadIdx.x; idx < 3136; idx += 256) {
    int w = idx / 56, h = idx - w * 56;
    xb[((size_t)(n * 56 + w) * 128 + c) * 56 + h] = t[h][w];  // coalesced write (h contiguous)
  }
}

// tmp (896,128,56) -> out (16,128,56,56): out[n][c][h][w] = tmp[n*56+w][c][h]
__global__ __launch_bounds__(256) void k_transpose_out(const float* __restrict__ tmp,
                                                       float* __restrict__ out) {
  int nc = blockIdx.x;
  int n = nc >> 7, c = nc & 127;
  __shared__ float t[56][57];
  for (int idx = threadIdx.x; idx < 3136; idx += 256) {
    int w = idx / 56, h = idx - w * 56;
    t[h][w] = tmp[((size_t)(n * 56 + w) * 128 + c) * 56 + h];  // coalesced read
  }
  __syncthreads();
  float* dst = out + (size_t)nc * 3136;
  for (int idx = threadIdx.x; idx < 3136; idx += 256)
    dst[idx] = t[idx / 56][idx % 56];        // coalesced write
}

// One block per (b,g). bid = g*896 + b  (so same-b blocks share bid%8 -> same XCD L2).
__global__ __launch_bounds__(256) void k_fused(
    const float* __restrict__ xb, const float* __restrict__ wq,
    const float* __restrict__ rel,
    const float* __restrict__ qg, const float* __restrict__ qb,
    const float* __restrict__ qm, const float* __restrict__ qv,
    const float* __restrict__ sg, const float* __restrict__ sb,
    const float* __restrict__ sm, const float* __restrict__ svar,
    const float* __restrict__ og, const float* __restrict__ ob,
    const float* __restrict__ om, const float* __restrict__ ov,
    float* __restrict__ tmp) {
  const int tid = threadIdx.x;
  const int g = blockIdx.x / 896;
  const int b = blockIdx.x - g * 896;

  // stage-1 region (xs + Ws) is dead after the GEMM; sim/simT alias it.
  __shared__ __align__(16) float sbuf[11264];   // 45 KB
  __shared__ __align__(16) float s_rel[32 * 112];
  __shared__ __align__(16) float s_qkv[32 * 56]; // q:0..7, k:8..15, v:16..31 (BN applied)
  __shared__ float s_qsc[32], s_qsh[32], s_osc[32], s_osh[32], s_ssc[3], s_ssh[3];

  float* xs   = sbuf;          // [128][56]
  float* Ws   = sbuf + 7168;   // [32][128]
  float* sim  = sbuf;          // [56][56]
  float* simT = sbuf + 3136;   // [56][60]  (simT[j][i] = softmaxed sim[i][j])

  // ---------- stage 0: staging ----------
  {
    const float4* src = (const float4*)(xb + (size_t)b * 7168);
    float4* dst = (float4*)xs;
#pragma unroll
    for (int i = 0; i < 7; ++i) dst[tid + i * 256] = src[tid + i * 256];
    const float4* wsrc = (const float4*)(wq + g * 4096);
    float4* wdst = (float4*)Ws;
#pragma unroll
    for (int i = 0; i < 4; ++i) wdst[tid + i * 256] = wsrc[tid + i * 256];
    for (int i = tid; i < 3552; i += 256) {
      int r = i / 111;
      s_rel[r * 112 + (i - r * 111)] = rel[i];
    }
    if (tid < 32) {
      int ch = g * 32 + tid;
      float sc = qg[ch] * rsqrtf(qv[ch] + EPSV);
      s_qsc[tid] = sc;
      s_qsh[tid] = qb[ch] - qm[ch] * sc;
      float so = og[ch] * rsqrtf(ov[ch] + EPSV);
      s_osc[tid] = so;
      s_osh[tid] = ob[ch] - om[ch] * so;
    }
    if (tid < 3) {
      int ch = tid * 8 + g;     // stacked sim channels: qk=g, qr=8+g, kr=16+g
      float ss = sg[ch] * rsqrtf(svar[ch] + EPSV);
      s_ssc[tid] = ss;
      s_ssh[tid] = sb[ch] - sm[ch] * ss;
    }
  }
  __syncthreads();

  // ---------- stage 1: qkv = BN(W_g @ xb[b]), 32x56 ----------
  if (tid < 224) {
    const int o0 = (tid / 14) * 2;
    const int h0 = (tid % 14) * 4;
    float a00 = 0, a01 = 0, a02 = 0, a03 = 0;
    float a10 = 0, a11 = 0, a12 = 0, a13 = 0;
    const float* w0p = &Ws[o0 * 128];
    const float* w1p = w0p + 128;
    for (int c = 0; c < 128; ++c) {
      const float4 xv = *(const float4*)&xs[c * 56 + h0];
      const float w0 = w0p[c], w1 = w1p[c];
      a00 = fmaf(w0, xv.x, a00); a01 = fmaf(w0, xv.y, a01);
      a02 = fmaf(w0, xv.z, a02); a03 = fmaf(w0, xv.w, a03);
      a10 = fmaf(w1, xv.x, a10); a11 = fmaf(w1, xv.y, a11);
      a12 = fmaf(w1, xv.z, a12); a13 = fmaf(w1, xv.w, a13);
    }
    float sc = s_qsc[o0], sh = s_qsh[o0];
    s_qkv[o0 * 56 + h0 + 0] = fmaf(a00, sc, sh);
    s_qkv[o0 * 56 + h0 + 1] = fmaf(a01, sc, sh);
    s_qkv[o0 * 56 + h0 + 2] = fmaf(a02, sc, sh);
    s_qkv[o0 * 56 + h0 + 3] = fmaf(a03, sc, sh);
    sc = s_qsc[o0 + 1]; sh = s_qsh[o0 + 1];
    s_qkv[(o0 + 1) * 56 + h0 + 0] = fmaf(a10, sc, sh);
    s_qkv[(o0 + 1) * 56 + h0 + 1] = fmaf(a11, sc, sh);
    s_qkv[(o0 + 1) * 56 + h0 + 2] = fmaf(a12, sc, sh);
    s_qkv[(o0 + 1) * 56 + h0 + 3] = fmaf(a13, sc, sh);
  }
  __syncthreads();

  // ---------- stage 2: sim[i][j] = bnA(qk)+bnB(qr)+bnC(kr) ----------
  {
    const float scA = s_ssc[0], shA = s_ssh[0];
    const float scB = s_ssc[1], shB = s_ssh[1];
    const float scC = s_ssc[2], shC = s_ssh[2];
    for (int t = tid; t < 784; t += 256) {
      const int i = t / 14;
      const int j0 = (t - i * 14) * 4;
      float qk0 = 0, qk1 = 0, qk2 = 0, qk3 = 0;
      float qr0 = 0, qr1 = 0, qr2 = 0, qr3 = 0;
      float kr0 = 0, kr1 = 0, kr2 = 0, kr3 = 0;
#pragma unroll
      for (int c = 0; c < 8; ++c) {
        const float qi = s_qkv[c * 56 + i];
        const float4 kj = *(const float4*)&s_qkv[(8 + c) * 56 + j0];
        const float* rq = &s_rel[c * 112 + i - j0 + 55];        // rq[-dj] = rel[c][i-(j0+dj)+55]
        const float* rk = &s_rel[(8 + c) * 112 + j0 - i + 55];  // rk[dj]  = rel[8+c][(j0+dj)-i+55]
        qk0 = fmaf(qi, kj.x, qk0); qk1 = fmaf(qi, kj.y, qk1);
        qk2 = fmaf(qi, kj.z, qk2); qk3 = fmaf(qi, kj.w, qk3);
        qr0 = fmaf(qi, rq[0], qr0);  qr1 = fmaf(qi, rq[-1], qr1);
        qr2 = fmaf(qi, rq[-2], qr2); qr3 = fmaf(qi, rq[-3], qr3);
        kr0 = fmaf(kj.x, rk[0], kr0); kr1 = fmaf(kj.y, rk[1], kr1);
        kr2 = fmaf(kj.z, rk[2], kr2); kr3 = fmaf(kj.w, rk[3], kr3);
      }
      float4 o4;
      o4.x = fmaf(qk0, scA, shA) + fmaf(qr0, scB, shB) + fmaf(kr0, scC, shC);
      o4.y = fmaf(qk1, scA, shA) + fmaf(qr1, scB, shB) + fmaf(kr1, scC, shC);
      o4.z = fmaf(qk2, scA, shA) + fmaf(qr2, scB, shB) + fmaf(kr2, scC, shC);
      o4.w = fmaf(qk3, scA, shA) + fmaf(qr3, scB, shB) + fmaf(kr3, scC, shC);
      *(float4*)&sim[i * 56 + j0] = o4;
    }
  }
  __syncthreads();

  // ---------- stage 3: row softmax (axis j) + transpose into simT ----------
  {
    const int lane = tid & 63;
    const int wv = tid >> 6;
    for (int i = wv; i < 56; i += 4) {
      float v = (lane < 56) ? sim[i * 56 + lane] : -3.0e38f;
      float m = v;
#pragma unroll
      for (int off = 32; off > 0; off >>= 1) m = fmaxf(m, __shfl_xor(m, off));
      float e = (lane < 56) ? __expf(v - m) : 0.0f;
      float s = e;
#pragma unroll
      for (int off = 32; off > 0; off >>= 1) s += __shfl_xor(s, off);
      if (lane < 56) simT[lane * 60 + i] = e / s;
    }
  }
  __syncthreads();

  // ---------- stage 4: sv/sve + out BN + pair-sum, write tmp[b][g*16+c][i] ----------
  if (tid < 224) {
    const int c = tid / 14;                 // 0..15
    const int i0 = (tid - c * 14) * 4;
    float sv0 = 0, sv1 = 0, sv2 = 0, sv3 = 0;
    float se0 = 0, se1 = 0, se2 = 0, se3 = 0;
    const float* vrow = &s_qkv[(16 + c) * 56];
    const float* rv = &s_rel[(16 + c) * 112 + 55 + i0];  // (rv - j)[di] = rel[16+c][(i0+di)-j+55]
    for (int j = 0; j < 56; ++j) {
      const float vj = vrow[j];
      const float4 p = *(const float4*)&simT[j * 60 + i0];
      sv0 = fmaf(p.x, vj, sv0); sv1 = fmaf(p.y, vj, sv1);
      sv2 = fmaf(p.z, vj, sv2); sv3 = fmaf(p.w, vj, sv3);
      const float* r = rv - j;
      se0 = fmaf(p.x, r[0], se0); se1 = fmaf(p.y, r[1], se1);
      se2 = fmaf(p.z, r[2], se2); se3 = fmaf(p.w, r[3], se3);
    }
    const float sc0 = s_osc[2 * c],     sh0 = s_osh[2 * c];
    const float sc1 = s_osc[2 * c + 1], sh1 = s_osh[2 * c + 1];
    float4 o4;
    o4.x = fmaf(sv0, sc0, sh0) + fmaf(se0, sc1, sh1);
    o4.y = fmaf(sv1, sc0, sh0) + fmaf(se1, sc1, sh1);
    o4.z = fmaf(sv2, sc0, sh0) + fmaf(se2, sc1, sh1);
    o4.w = fmaf(sv3, sc0, sh0) + fmaf(se3, sc1, sh1);
    const int oc = g * 16 + c;
    *(float4*)&tmp[((size_t)b * 128 + oc) * 56 + i0] = o4;
  }
}

extern "C" void kernel_launch(void* const* d_in, const int* in_sizes, int n_in,
                              void* d_out, int out_size, void* d_ws, size_t ws_size,
                              hipStream_t stream) {
  const float* x   = (const float*)d_in[0];
  const float* wq  = (const float*)d_in[1];
  const float* rel = (const float*)d_in[2];
  const float* qg = (const float*)d_in[3];
  const float* qb = (const float*)d_in[4];
  const float* qm = (const float*)d_in[5];
  const float* qv = (const float*)d_in[6];
  const float* sg = (const float*)d_in[7];
  const float* sb = (const float*)d_in[8];
  const float* sm = (const float*)d_in[9];
  const float* sv = (const float*)d_in[10];
  const float* og = (const float*)d_in[11];
  const float* ob = (const float*)d_in[12];
  const float* om = (const float*)d_in[13];
  const float* ov = (const float*)d_in[14];
  float* out = (float*)d_out;

  // Reuse d_out as the xb staging buffer (same size: 896*128*56 floats);
  // workspace holds tmp (25.7 MB).
  float* xbuf = out;
  float* tmp = (float*)d_ws;

  k_transpose_in<<<2048, 256, 0, stream>>>(x, xbuf);
  k_fused<<<7168, 256, 0, stream>>>(xbuf, wq, rel,
                                    qg, qb, qm, qv,
                                    sg, sb, sm, sv,
                                    og, ob, om, ov, tmp);
  k_transpose_out<<<2048, 256, 0, stream>>>(tmp, out);
}